// Round 8
// baseline (431.225 us; speedup 1.0000x reference)
//
#include <hip/hip_runtime.h>

typedef unsigned short ushort_t;
typedef unsigned char u8;
typedef short bf16x8 __attribute__((ext_vector_type(8)));
typedef float f32x4 __attribute__((ext_vector_type(4)));

#define T_DIM 4
#define B_DIM 32
#define C_DIM 512
#define N_DIM 256

__device__ __forceinline__ float bf2f(ushort_t u) {
  union { unsigned int i; float f; } x;
  x.i = ((unsigned int)u) << 16;
  return x.f;
}
__device__ __forceinline__ ushort_t f2bf(float f) {
  unsigned int u = __float_as_uint(f);
  u = (u + 0x7FFFu + ((u >> 16) & 1u)) >> 16;
  return (ushort_t)u;
}

// async global->LDS DMA, 16B per lane, lane i lands at ldsbase + i*16
__device__ __forceinline__ void gload16(const void* g, void* l) {
  __builtin_amdgcn_global_load_lds(
      (const __attribute__((address_space(1))) unsigned int*)g,
      (__attribute__((address_space(3))) unsigned int*)l, 16, 0, 0);
}

// 0/1 spike bytes (2 per word, at bytes 0 and 2) -> 2 bf16 halfwords.
// operands < 2^24 so v_mul_u32_u24 (full-rate, literal-in-src0) is exact.
__device__ __forceinline__ unsigned int spike2bf(unsigned int w) {
  unsigned int r;
  asm("v_mul_u32_u24 %0, 0x3f80, %1" : "=v"(r) : "v"(w));
  return r;
}
__device__ __forceinline__ bf16x8 expand_spikes(uint2 raw) {
  union { bf16x8 v; unsigned int u[4]; } bu;
  bu.u[0] = spike2bf(__builtin_amdgcn_perm(0u, raw.x, 0x05010400u));
  bu.u[1] = spike2bf(__builtin_amdgcn_perm(0u, raw.x, 0x07030602u));
  bu.u[2] = spike2bf(__builtin_amdgcn_perm(0u, raw.y, 0x05010400u));
  bu.u[3] = spike2bf(__builtin_amdgcn_perm(0u, raw.y, 0x07030602u));
  return bu.v;
}

// ---------------------------------------------------------------------------
// K0: split fp32 weights into 3 bf16 planes (hi, mid, lo). W ~= hi+mid+lo.
// (K2/K5 consume only hi+mid.)
// ---------------------------------------------------------------------------
__global__ __launch_bounds__(256) void k0_split(
    const float* __restrict__ Wq, const float* __restrict__ Wk,
    const float* __restrict__ Wv, const float* __restrict__ Wp,
    ushort_t* __restrict__ Sqkv, ushort_t* __restrict__ Sp)
{
  int gid = blockIdx.x * 256 + threadIdx.x;   // [0, 131072)
  int w = gid >> 15;
  int off = (gid & 32767) * 8;
  const float* src = (w == 0) ? Wq : ((w == 1) ? Wk : ((w == 2) ? Wv : Wp));
  ushort_t* dst = (w < 3) ? (Sqkv + (size_t)w * 3 * 262144) : Sp;
  float wv[8];
  *(float4*)&wv[0] = *(const float4*)(src + off);
  *(float4*)&wv[4] = *(const float4*)(src + off + 4);
  ushort_t hi[8], mi[8], lo[8];
#pragma unroll
  for (int i = 0; i < 8; i++) {
    float f = wv[i];
    ushort_t h = f2bf(f);  float r  = f - bf2f(h);
    ushort_t m = f2bf(r);  float r2 = r - bf2f(m);
    ushort_t l = f2bf(r2);
    hi[i] = h; mi[i] = m; lo[i] = l;
  }
  *(uint4*)(dst + off)              = *(uint4*)&hi[0];
  *(uint4*)(dst + 262144 + off)     = *(uint4*)&mi[0];
  *(uint4*)(dst + 2 * 262144 + off) = *(uint4*)&lo[0];
}

// ---------------------------------------------------------------------------
// K1: shortcut LIF on x [T,B,C,N] (fp32) -> spikes transposed xsT8 [T,B,N,C] u8
// ---------------------------------------------------------------------------
__global__ __launch_bounds__(256) void k1_shortcut_lif(
    const float* __restrict__ x, u8* __restrict__ xsT8)
{
  const int n0 = blockIdx.x * 64;
  const int c0 = blockIdx.y * 64;
  const int b  = blockIdx.z;
  __shared__ u8 sm[64][80];
  const int tid = threadIdx.x;
  const int r  = tid >> 2;
  const int j0 = (tid & 3) * 16;
  float v[16];
#pragma unroll
  for (int i = 0; i < 16; i++) v[i] = 0.f;
  for (int t = 0; t < T_DIM; t++) {
    const float* xp = x + ((((size_t)t * B_DIM + b) * C_DIM) + c0 + r) * N_DIM + n0 + j0;
    float xv[16];
    *(float4*)&xv[0]  = *(const float4*)xp;
    *(float4*)&xv[4]  = *(const float4*)(xp + 4);
    *(float4*)&xv[8]  = *(const float4*)(xp + 8);
    *(float4*)&xv[12] = *(const float4*)(xp + 12);
    __syncthreads();
#pragma unroll
    for (int i = 0; i < 16; i++) {
      float nv = v[i] + (xv[i] - v[i]) * 0.5f;
      bool s = (nv >= 1.0f);
      v[i] = s ? 0.f : nv;
      sm[j0 + i][r] = s ? (u8)1 : (u8)0;
    }
    __syncthreads();
    union { uint4 u; u8 b[16]; } ov;
#pragma unroll
    for (int i = 0; i < 16; i++) ov.b[i] = sm[r][j0 + i];
    u8* op = xsT8 + ((((size_t)t * B_DIM + b) * N_DIM) + n0 + r) * C_DIM + c0 + j0;
    *(uint4*)op = ov.u;
  }
}

// ---------------------------------------------------------------------------
// K2: QKV conv1x1 + BN + LIF. 512 threads (8 waves), 64m x 256n block tile,
// wave tile 32m x 64n (2 m-strips x 4 n-strips; acc[2][4]). TWO bf16 planes.
// Tile chosen to halve spike-expansion VALU (4 B-frags/wave/step, B-row
// redundancy 2x) while A redundancy rises on the zero-VALU bf16 path;
// LDS reads/block/step drop 80->64 KB. Swizzle constants lane-invariant.
// Depth-2 counted-vmcnt pipeline: 4 rotating LDS buffers, 1 s_barrier/step,
// steady s_waitcnt vmcnt(4). Uniform 2 gload16/wave/stage.
// Outputs:
//    q -> qs8T[t,b,n,c] u8 (transposed, uchar4 stores)  [K4 B-operand]
//    k -> ks8 [t,b,c,n] u8                              [K3 A-operand]
//    v -> vout[t,b,h,n,d] fp32 0/1 (out1)  +  vs8T[t,b,h,e,n] u8 [K3 B-op]
// ---------------------------------------------------------------------------
__global__ __launch_bounds__(512, 4) void k2_qkv(
    const u8* __restrict__ xsT8, const ushort_t* __restrict__ Sqkv,
    const float* __restrict__ qsc, const float* __restrict__ qbi,
    const float* __restrict__ ksc, const float* __restrict__ kbi,
    const float* __restrict__ vsc, const float* __restrict__ vbi,
    u8* __restrict__ qs8T, u8* __restrict__ ks8, float* __restrict__ vout,
    u8* __restrict__ vs8T)
{
  const int lin = blockIdx.x + blockIdx.y * 24;        // 0..767
  const int b   = (lin & 7) | (((lin >> 3) & 3) << 3); // XCD = lin%8 = b%8
  const int mt  = lin >> 5;                            // 0..23
  const int branch = mt >> 3;         // 0=q 1=k 2=v
  const int mloc = (mt & 7) * 64;     // within branch's 512
  const ushort_t* Ws = Sqkv + (size_t)branch * 3 * 262144;
  const float* scp = (branch == 0) ? qsc : ((branch == 1) ? ksc : vsc);
  const float* bip = (branch == 0) ? qbi : ((branch == 1) ? kbi : vbi);

  __shared__ alignas(16) ushort_t As[4][2][64][32];   // 32 KB, linear dest
  __shared__ alignas(16) u8 Bs8[4][256][32];          // 32 KB, linear dest

  const int tid  = threadIdx.x;
  const int lane = tid & 63;
  const int wave = tid >> 6;
  const int wm   = wave >> 2;          // 0..1 m-strip (32 rows)
  const int wn   = wave & 3;           // 0..3 n-strip (64 cols)
  const int frow = lane & 15;
  const int fsl  = lane >> 4;          // 8-elem slot 0..3
  // lane-invariant frag swizzles (row bits 1..3 come from frow only)
  const int aswc = (fsl ^ ((frow >> 1) & 3)) * 8;                              // ushort units
  const int bswc = (((fsl >> 1) ^ (((frow >> 2) ^ (frow >> 3)) & 1)) << 4)
                 + ((fsl & 1) << 3);                                           // bytes

  const u8* Bb0 = xsT8 + (size_t)b * N_DIM * C_DIM;

  const int a0p = wave >> 2, a0q = wave & 3;
  const int arl = lane >> 2;                              // row within 16
  const int acl = (((lane & 3) ^ ((arl >> 1) & 3)) * 8);  // swizzled 16B slot (ushort units)
  const int brl = lane >> 1;                              // row within 32
  const int bcl = (((lane & 1) ^ ((brl >> 2) & 1) ^ ((brl >> 3) & 1)) * 16); // swizzled 16B half (bytes)
  const int cbx = wave;

#define K2_STAGE(s_) {                                                                     \
    const int ss_ = (s_);                                                                  \
    const int t_ = ss_ >> 4; const int kb_ = (ss_ & 15) * 32; const int bf_ = ss_ & 3;     \
    gload16(Ws + (size_t)a0p * 262144 + (size_t)(mloc + a0q * 16 + arl) * 512 + kb_ + acl, \
            &As[bf_][a0p][a0q * 16][0]);                                                   \
    gload16(Bb0 + (size_t)t_ * (B_DIM * N_DIM * C_DIM) + (size_t)(cbx * 32 + brl) * 512 + kb_ + bcl, \
            &Bs8[bf_][cbx * 32][0]);                                                       \
  }

  f32x4 acc[8];
  float vst[32];
#pragma unroll
  for (int i = 0; i < 32; i++) vst[i] = 0.f;
#pragma unroll
  for (int j = 0; j < 8; j++) acc[j] = (f32x4){0.f, 0.f, 0.f, 0.f};

  const int crow0 = (lane >> 4) * 4;
  const int cn    = lane & 15;
  float sc8[2][4], bi8[2][4];
#pragma unroll
  for (int mi = 0; mi < 2; mi++)
#pragma unroll
    for (int r = 0; r < 4; r++) {
      int c = mloc + wm * 32 + mi * 16 + crow0 + r;
      sc8[mi][r] = scp[c]; bi8[mi][r] = bip[c];
    }

  K2_STAGE(0);
  K2_STAGE(1);

  for (int s = 0; s < 64; s++) {
    const int cur = s & 3;
    if (s < 62) K2_STAGE(s + 2);

    if (s < 62)       asm volatile("s_waitcnt vmcnt(4)" ::: "memory");
    else if (s == 62) asm volatile("s_waitcnt vmcnt(2)" ::: "memory");
    else              asm volatile("s_waitcnt vmcnt(0)" ::: "memory");
    __builtin_amdgcn_s_barrier();
    __builtin_amdgcn_sched_barrier(0);

    bf16x8 bfr[4];
#pragma unroll
    for (int nj = 0; nj < 4; nj++)
      bfr[nj] = expand_spikes(*(const uint2*)&Bs8[cur][wn * 64 + nj * 16 + frow][bswc]);

#pragma unroll
    for (int mi = 0; mi < 2; mi++) {
      const int ar = wm * 32 + mi * 16 + frow;
      bf16x8 a0 = *(const bf16x8*)&As[cur][0][ar][aswc];
      bf16x8 a1 = *(const bf16x8*)&As[cur][1][ar][aswc];
#pragma unroll
      for (int nj = 0; nj < 4; nj++) {
        acc[mi * 4 + nj] = __builtin_amdgcn_mfma_f32_16x16x32_bf16(a0, bfr[nj], acc[mi * 4 + nj], 0, 0, 0);
        acc[mi * 4 + nj] = __builtin_amdgcn_mfma_f32_16x16x32_bf16(a1, bfr[nj], acc[mi * 4 + nj], 0, 0, 0);
      }
    }

    if ((s & 15) == 15) {
      const int t = s >> 4;
      const size_t tb = (size_t)t * B_DIM + b;
      if (branch == 0) {
#pragma unroll
        for (int mi = 0; mi < 2; mi++) {
          const int c0 = mloc + wm * 32 + mi * 16 + crow0;
#pragma unroll
          for (int nj = 0; nj < 4; nj++) {
            const int n = wn * 64 + nj * 16 + cn;
            u8 sv[4];
#pragma unroll
            for (int r = 0; r < 4; r++) {
              float y = acc[mi * 4 + nj][r] * sc8[mi][r] + bi8[mi][r];
              const int vi = (mi * 4 + nj) * 4 + r;
              float v = vst[vi];
              v = v + (y - v) * 0.5f;
              bool sp = (v >= 1.0f);
              vst[vi] = sp ? 0.f : v;
              sv[r] = sp ? (u8)1 : (u8)0;
            }
            *(uchar4*)(qs8T + (tb * N_DIM + n) * C_DIM + c0) =
                make_uchar4(sv[0], sv[1], sv[2], sv[3]);
          }
        }
      } else if (branch == 1) {
#pragma unroll
        for (int mi = 0; mi < 2; mi++)
#pragma unroll
          for (int r = 0; r < 4; r++) {
            const int c = mloc + wm * 32 + mi * 16 + crow0 + r;
#pragma unroll
            for (int nj = 0; nj < 4; nj++) {
              const int n = wn * 64 + nj * 16 + cn;
              float y = acc[mi * 4 + nj][r] * sc8[mi][r] + bi8[mi][r];
              const int vi = (mi * 4 + nj) * 4 + r;
              float v = vst[vi];
              v = v + (y - v) * 0.5f;
              bool sp = (v >= 1.0f);
              vst[vi] = sp ? 0.f : v;
              ks8[(tb * C_DIM + c) * N_DIM + n] = sp ? (u8)1 : (u8)0;
            }
          }
      } else {
        const int hv = mloc >> 6;
#pragma unroll
        for (int mi = 0; mi < 2; mi++) {
          const int d0 = wm * 32 + mi * 16 + crow0;
#pragma unroll
          for (int nj = 0; nj < 4; nj++) {
            const int n = wn * 64 + nj * 16 + cn;
            float ov[4];
            u8 sv[4];
#pragma unroll
            for (int r = 0; r < 4; r++) {
              float y = acc[mi * 4 + nj][r] * sc8[mi][r] + bi8[mi][r];
              const int vi = (mi * 4 + nj) * 4 + r;
              float v = vst[vi];
              v = v + (y - v) * 0.5f;
              bool sp = (v >= 1.0f);
              vst[vi] = sp ? 0.f : v;
              ov[r] = sp ? 1.0f : 0.0f;
              sv[r] = sp ? (u8)1 : (u8)0;
            }
            *(float4*)(vout + ((tb * 8 + hv) * N_DIM + n) * 64 + d0) =
                make_float4(ov[0], ov[1], ov[2], ov[3]);
#pragma unroll
            for (int r = 0; r < 4; r++)
              vs8T[((tb * 8 + hv) * 64 + d0 + r) * N_DIM + n] = sv[r];
          }
        }
      }
#pragma unroll
      for (int j = 0; j < 8; j++) acc[j] = (f32x4){0.f, 0.f, 0.f, 0.f};
    }
  }
#undef K2_STAGE
}

// ---------------------------------------------------------------------------
// K3 (MFMA): attn[d,e] = (1/16) * sum_{t,n} K[d,tn] * V[tn,e].
// A = ks8 rows [d][n] u8; B = vs8T rows [e][n] u8 (V^T). 4 waves, K=512
// (16 k-steps of 32), depth-2 counted-vmcnt (1 gload16/wave/stage).
// Output: attnT2 = attn^T split into EXACT 2-plane bf16 (counts/16 < 2^11),
// k-step-blocked layout [blk][p][ks2][e][32d] so K4's A-reads are the
// standard 64B-row swizzled geometry.
// ---------------------------------------------------------------------------
__global__ __launch_bounds__(256) void k3_attn(
    const u8* __restrict__ ks8, const u8* __restrict__ vs8T,
    ushort_t* __restrict__ attnT2)
{
  const int h  = blockIdx.x;
  const int b  = blockIdx.y;
  const int ch = blockIdx.z;
  __shared__ alignas(16) u8 Ks[4][64][32];
  __shared__ alignas(16) u8 Vs[4][64][32];
  const int tid  = threadIdx.x;
  const int lane = tid & 63;
  const int wave = tid >> 6;        // 0..3
  const int wrow = wave * 16;       // d strip
  const int frow = lane & 15;
  const int fsl  = lane >> 4;
  const int brl  = lane >> 1;
  const int bcl  = (((lane & 1) ^ ((brl >> 2) & 1) ^ ((brl >> 3) & 1)) * 16);

#define K3_STAGE(s_) {                                                                     \
    const int ss_ = (s_);                                                                  \
    const int t_ = ch * 2 + (ss_ >> 3); const int kb_ = (ss_ & 7) * 32; const int bf_ = ss_ & 3; \
    if (wave < 2)                                                                          \
      gload16(ks8 + ((((size_t)t_ * B_DIM + b) * C_DIM) + h * 64 + wave * 32 + brl) * N_DIM + kb_ + bcl, \
              &Ks[bf_][wave * 32][0]);                                                     \
    else                                                                                   \
      gload16(vs8T + ((((size_t)t_ * B_DIM + b) * 8 + h) * 64 + (wave - 2) * 32 + brl) * N_DIM + kb_ + bcl, \
              &Vs[bf_][(wave - 2) * 32][0]);                                               \
  }

  f32x4 acc[4];
#pragma unroll
  for (int i = 0; i < 4; i++) acc[i] = (f32x4){0.f, 0.f, 0.f, 0.f};

  K3_STAGE(0);
  K3_STAGE(1);

  for (int s = 0; s < 16; s++) {
    const int cur = s & 3;
    if (s < 14) K3_STAGE(s + 2);

    if (s < 14)       asm volatile("s_waitcnt vmcnt(2)" ::: "memory");
    else if (s == 14) asm volatile("s_waitcnt vmcnt(1)" ::: "memory");
    else              asm volatile("s_waitcnt vmcnt(0)" ::: "memory");
    __builtin_amdgcn_s_barrier();
    __builtin_amdgcn_sched_barrier(0);

    const int arow = wrow + frow;
    const int axx  = ((arow >> 2) ^ (arow >> 3)) & 1;
    const int asw  = (((fsl >> 1) ^ axx) << 4) + ((fsl & 1) << 3);
    bf16x8 af = expand_spikes(*(const uint2*)&Ks[cur][arow][asw]);

#pragma unroll
    for (int nt = 0; nt < 4; nt++) {
      const int row = nt * 16 + frow;
      const int bx  = ((row >> 2) ^ (row >> 3)) & 1;
      const int bsw = (((fsl >> 1) ^ bx) << 4) + ((fsl & 1) << 3);
      bf16x8 bv = expand_spikes(*(const uint2*)&Vs[cur][row][bsw]);
      acc[nt] = __builtin_amdgcn_mfma_f32_16x16x32_bf16(af, bv, acc[nt], 0, 0, 0);
    }
  }

  // epilogue: C[d][e] -> attnT2[e][d] as 2 exact bf16 planes.
  const int cn    = lane & 15;
  const int crow0 = (lane >> 4) * 4;
  const int d     = wrow + crow0;       // 4 consecutive via r
  const int ks2   = d >> 5;
  const int dl    = d & 31;
  const size_t blk = ((size_t)(ch * B_DIM + b) * 8 + h);
#pragma unroll
  for (int nt = 0; nt < 4; nt++) {
    const int e = nt * 16 + cn;
    union { ushort_t sv[4]; uint2 u; } H, M;
#pragma unroll
    for (int r = 0; r < 4; r++) {
      float a = acc[nt][r] * 0.0625f;
      ushort_t hi = f2bf(a);
      float m = a - bf2f(hi);
      H.sv[r] = hi;
      M.sv[r] = f2bf(m);
    }
    *(uint2*)(attnT2 + ((blk * 2 + 0) * 2 + ks2) * 2048 + (size_t)e * 32 + dl) = H.u;
    *(uint2*)(attnT2 + ((blk * 2 + 1) * 2 + ks2) * 2048 + (size_t)e * 32 + dl) = M.u;
  }
#undef K3_STAGE
}

// ---------------------------------------------------------------------------
// K4 (MFMA): out[e,n] = sum_d attnT[e,d] * q[d,n]; LIF(0.5) over t in regs;
// -> x2sT8[t,b,n,c] u8 (uchar4 along c). A = attnT2 planes (both ch staged
// in prologue, 32 KB); B = qs8T rows [n][c] u8, staged per k-step (m97-style
// depth-1). 4 waves, wave tile 16e x 128n, acc[8], vst[32]. nc splits N.
// Exact vs scalar version (fp32 MFMA of integers/16 < 2^15).
// ---------------------------------------------------------------------------
__global__ __launch_bounds__(256) void k4_out_lif(
    const u8* __restrict__ qs8T, const ushort_t* __restrict__ attnT2,
    u8* __restrict__ x2sT8)
{
  const int h  = blockIdx.x;
  const int b  = blockIdx.y;
  const int nc = blockIdx.z;   // 0..1
  __shared__ alignas(16) ushort_t As[2][2][2][64][32];  // [ch][p][ks][e][32d] 32 KB
  __shared__ alignas(16) u8 Bs[2][128][32];             // 8 KB
  const int tid  = threadIdx.x;
  const int lane = tid & 63;
  const int wave = tid >> 6;        // 0..3
  const int wrow = wave * 16;       // e strip
  const int frow = lane & 15;
  const int fsl  = lane >> 4;
  const int arl  = lane >> 2;
  const int acl  = (((lane & 3) ^ ((arl >> 1) & 3)) * 8);
  const int brl  = lane >> 1;
  const int bcl  = (((lane & 1) ^ ((brl >> 2) & 1) ^ ((brl >> 3) & 1)) * 16);

#define K4_STAGEB(s_) {                                                                    \
    const int ss_ = (s_); const int t_ = ss_ >> 1; const int ks_ = ss_ & 1;                \
    gload16(qs8T + (((size_t)t_ * B_DIM + b) * N_DIM + nc * 128 + wave * 32 + brl) * C_DIM \
                 + h * 64 + ks_ * 32 + bcl,                                                \
            &Bs[ss_ & 1][wave * 32][0]);                                                   \
  }

  // prologue: stage A for BOTH ch (8 chunks/wave) + B(0).
#pragma unroll
  for (int i = 0; i < 8; i++) {
    const int c  = wave * 8 + i;
    const int chb = c >> 4, c4 = c & 15;
    const int p = c4 >> 3, ks = (c4 >> 2) & 1, g = c4 & 3;
    const size_t blk = ((size_t)(chb * B_DIM + b) * 8 + h);
    gload16(attnT2 + (((blk * 2 + p) * 2 + ks) * 64 + g * 16 + arl) * 32 + acl,
            &As[chb][p][ks][g * 16][0]);
  }
  K4_STAGEB(0);
  asm volatile("s_waitcnt vmcnt(0)" ::: "memory");
  __builtin_amdgcn_s_barrier();
  __builtin_amdgcn_sched_barrier(0);

  f32x4 acc[8];
  float vst[32];
#pragma unroll
  for (int i = 0; i < 32; i++) vst[i] = 0.f;

  const int cn    = lane & 15;
  const int crow0 = (lane >> 4) * 4;

  for (int sg = 0; sg < 8; sg++) {
    const int cur = sg & 1;
    if (sg < 7) K4_STAGEB(sg + 1);

    const int chb = sg >> 2, ks = sg & 1;
    if (ks == 0) {
#pragma unroll
      for (int j = 0; j < 8; j++) acc[j] = (f32x4){0.f, 0.f, 0.f, 0.f};
    }

    bf16x8 af[2];
    const int ar = wrow + frow;
    const int asw = (fsl ^ ((ar >> 1) & 3)) * 8;
#pragma unroll
    for (int p = 0; p < 2; p++) af[p] = *(const bf16x8*)&As[chb][p][ks][ar][asw];

#pragma unroll
    for (int j = 0; j < 8; j++) {
      const int row = j * 16 + frow;
      const int bx  = ((row >> 2) ^ (row >> 3)) & 1;
      const int bsw = (((fsl >> 1) ^ bx) << 4) + ((fsl & 1) << 3);
      bf16x8 bv = expand_spikes(*(const uint2*)&Bs[cur][row][bsw]);
#pragma unroll
      for (int p = 0; p < 2; p++)
        acc[j] = __builtin_amdgcn_mfma_f32_16x16x32_bf16(af[p], bv, acc[j], 0, 0, 0);
    }

    if (ks == 1) {
      const int t = sg >> 1;
      const size_t tb = (size_t)t * B_DIM + b;
#pragma unroll
      for (int j = 0; j < 8; j++) {
        const int n = nc * 128 + j * 16 + cn;
        u8 sv[4];
#pragma unroll
        for (int r = 0; r < 4; r++) {
          const int vi = j * 4 + r;
          float y = acc[j][r];
          float nv = vst[vi] + (y - vst[vi]) * 0.5f;
          bool sp = (nv >= 0.5f);
          vst[vi] = sp ? 0.f : nv;
          sv[r] = sp ? (u8)1 : (u8)0;
        }
        *(uchar4*)(x2sT8 + (tb * N_DIM + n) * C_DIM + h * 64 + wrow + crow0) =
            make_uchar4(sv[0], sv[1], sv[2], sv[3]);
      }
    }

    asm volatile("s_waitcnt vmcnt(0)" ::: "memory");
    __builtin_amdgcn_s_barrier();
    __builtin_amdgcn_sched_barrier(0);
  }
#undef K4_STAGEB
}

// ---------------------------------------------------------------------------
// K5: proj conv1x1 (+bp)*scale+bias + residual -> out0 fp32. k2 engine:
// 2 planes, wave tile 32m x 64n, depth-2 counted-vmcnt, 4 LDS buffers,
// uniform 2 loads/wave. Grid (tb, mt): XCD = tb%8.
// ---------------------------------------------------------------------------
__global__ __launch_bounds__(512, 4) void k5_proj(
    const u8* __restrict__ x2sT8, const ushort_t* __restrict__ Sp,
    const float* __restrict__ bp, const float* __restrict__ psc,
    const float* __restrict__ pbi,
    const float* __restrict__ x, float* __restrict__ out0)
{
  const int tb = blockIdx.x;   // 0..127 (fast dim -> XCD = tb%8)
  const int mt = blockIdx.y;   // 0..7
  const int mloc = mt * 64;

  __shared__ alignas(16) ushort_t As[4][2][64][32];
  __shared__ alignas(16) u8 Bs8[4][256][32];

  const int tid  = threadIdx.x;
  const int lane = tid & 63;
  const int wave = tid >> 6;
  const int wm   = wave >> 2;
  const int wn   = wave & 3;
  const int frow = lane & 15;
  const int fsl  = lane >> 4;
  const int aswc = (fsl ^ ((frow >> 1) & 3)) * 8;
  const int bswc = (((fsl >> 1) ^ (((frow >> 2) ^ (frow >> 3)) & 1)) << 4)
                 + ((fsl & 1) << 3);

  const u8* Bb = x2sT8 + (size_t)tb * N_DIM * C_DIM;

  const int a0p = wave >> 2, a0q = wave & 3;
  const int arl = lane >> 2;
  const int acl = (((lane & 3) ^ ((arl >> 1) & 3)) * 8);
  const int brl = lane >> 1;
  const int bcl = (((lane & 1) ^ ((brl >> 2) & 1) ^ ((brl >> 3) & 1)) * 16);
  const int cbx = wave;

#define K5_STAGE(s_) {                                                                     \
    const int ss_ = (s_); const int kb_ = ss_ * 32; const int bf_ = ss_ & 3;               \
    gload16(Sp + (size_t)a0p * 262144 + (size_t)(mloc + a0q * 16 + arl) * 512 + kb_ + acl, \
            &As[bf_][a0p][a0q * 16][0]);                                                   \
    gload16(Bb + (size_t)(cbx * 32 + brl) * 512 + kb_ + bcl, &Bs8[bf_][cbx * 32][0]);      \
  }

  f32x4 acc[8];
#pragma unroll
  for (int j = 0; j < 8; j++) acc[j] = (f32x4){0.f, 0.f, 0.f, 0.f};

  K5_STAGE(0);
  K5_STAGE(1);

  for (int s = 0; s < 16; s++) {
    const int cur = s & 3;
    if (s < 14) K5_STAGE(s + 2);

    if (s < 14)       asm volatile("s_waitcnt vmcnt(4)" ::: "memory");
    else if (s == 14) asm volatile("s_waitcnt vmcnt(2)" ::: "memory");
    else              asm volatile("s_waitcnt vmcnt(0)" ::: "memory");
    __builtin_amdgcn_s_barrier();
    __builtin_amdgcn_sched_barrier(0);

    bf16x8 bfr[4];
#pragma unroll
    for (int nj = 0; nj < 4; nj++)
      bfr[nj] = expand_spikes(*(const uint2*)&Bs8[cur][wn * 64 + nj * 16 + frow][bswc]);

#pragma unroll
    for (int mi = 0; mi < 2; mi++) {
      const int ar = wm * 32 + mi * 16 + frow;
      bf16x8 a0 = *(const bf16x8*)&As[cur][0][ar][aswc];
      bf16x8 a1 = *(const bf16x8*)&As[cur][1][ar][aswc];
#pragma unroll
      for (int nj = 0; nj < 4; nj++) {
        acc[mi * 4 + nj] = __builtin_amdgcn_mfma_f32_16x16x32_bf16(a0, bfr[nj], acc[mi * 4 + nj], 0, 0, 0);
        acc[mi * 4 + nj] = __builtin_amdgcn_mfma_f32_16x16x32_bf16(a1, bfr[nj], acc[mi * 4 + nj], 0, 0, 0);
      }
    }
  }

  const int crow0 = (lane >> 4) * 4;
  const int cn    = lane & 15;
#pragma unroll
  for (int mi = 0; mi < 2; mi++)
#pragma unroll
    for (int r = 0; r < 4; r++) {
      const int c = mloc + wm * 32 + mi * 16 + crow0 + r;
      const float scf = psc[c];
      const float bif = pbi[c];
      const float bpf = bp[c];
#pragma unroll
      for (int nj = 0; nj < 4; nj++) {
        const int n = wn * 64 + nj * 16 + cn;
        const size_t idx = ((size_t)tb * C_DIM + c) * N_DIM + n;
        out0[idx] = (acc[mi * 4 + nj][r] + bpf) * scf + bif + x[idx];
      }
    }
#undef K5_STAGE
}

// ---------------------------------------------------------------------------
// Memory map (race-free):
// d_out (128 MB): out0 bytes [0,64M) used as scratch until K5:
//   [0,16M)  xsT8 [K1->K2]   ; attnT2 8MB reuses [0,8M) [K3->K4] (xsT8 dead)
//   [16,32M) qs8T [K2->K4]
//   [32,48M) ks8  [K2->K3]
//   [48,64M) vs8T [K2->K3]
// out1 bytes [64,128M) = vout (fp32 v output, written by K2).
// d_ws (17.5 MB used):
//   [0,16M)   x2sT8 [K4->K5]; Sqkv 4.5MB aliases [0,4.5M) [K0->K2]
//             (safe: K2 reads Sqkv before K4 writes x2sT8)
//   [16,17.5M) Sp [K0->K5]
// ---------------------------------------------------------------------------
extern "C" void kernel_launch(void* const* d_in, const int* in_sizes, int n_in,
                              void* d_out, int out_size, void* d_ws, size_t ws_size,
                              hipStream_t stream) {
  const float* x   = (const float*)d_in[0];
  const float* Wq  = (const float*)d_in[1];
  const float* qsc = (const float*)d_in[2];
  const float* qbi = (const float*)d_in[3];
  const float* Wk  = (const float*)d_in[4];
  const float* ksc = (const float*)d_in[5];
  const float* kbi = (const float*)d_in[6];
  const float* Wv  = (const float*)d_in[7];
  const float* vsc = (const float*)d_in[8];
  const float* vbi = (const float*)d_in[9];
  const float* Wp  = (const float*)d_in[10];
  const float* bp  = (const float*)d_in[11];
  const float* psc = (const float*)d_in[12];
  const float* pbi = (const float*)d_in[13];

  float* out0 = (float*)d_out;
  float* out1 = out0 + 16777216;

  const size_t M16 = 16u * 1024u * 1024u;
  char* o0 = (char*)d_out;
  char* ws = (char*)d_ws;

  u8*       xsT8   = (u8*)(o0);
  ushort_t* attnT2 = (ushort_t*)(o0);
  u8*       qs8T   = (u8*)(o0 + M16);
  u8*       ks8    = (u8*)(o0 + 2 * M16);
  u8*       vs8T   = (u8*)(o0 + 3 * M16);
  u8*       x2sT8  = (u8*)(ws);
  ushort_t* Sqkv   = (ushort_t*)(ws);
  ushort_t* Sp     = (ushort_t*)(ws + M16);

  hipLaunchKernelGGL(k0_split,        dim3(512),        dim3(256), 0, stream,
                     Wq, Wk, Wv, Wp, Sqkv, Sp);
  hipLaunchKernelGGL(k1_shortcut_lif, dim3(4, 8, 32),   dim3(256), 0, stream, x, xsT8);
  hipLaunchKernelGGL(k2_qkv,          dim3(24, 32),     dim3(512), 0, stream,
                     xsT8, Sqkv, qsc, qbi, ksc, kbi, vsc, vbi, qs8T, ks8, out1, vs8T);
  hipLaunchKernelGGL(k3_attn,         dim3(8, 32, 2),   dim3(256), 0, stream,
                     ks8, vs8T, attnT2);
  hipLaunchKernelGGL(k4_out_lif,      dim3(8, 32, 2),   dim3(256), 0, stream,
                     qs8T, attnT2, x2sT8);
  hipLaunchKernelGGL(k5_proj,         dim3(128, 8),     dim3(512), 0, stream,
                     x2sT8, Sp, bp, psc, pbi, x, out0);
}